// Round 13
// baseline (48.443 us; speedup 1.0000x reference)
//
#include <hip/hip_runtime.h>

#define STEP 10
#define NCH  256                 // 128*2 flattened channels = DP "batches"
#define CSCL (-144.2695041f)     // -(1/GAMMA)*log2(e): scale into log2 domain
#define GLN2 (-0.00693147181f)   // -GAMMA*ln(2) == 1/CSCL (to 7e-10 rel)
#define BIGP (-1.442695041e12f)  // 1e10 * CSCL : boundary "BIG" in scaled domain
#define YOFF 64                  // pad: y idx = sb+J-i-1 >= -63
#define YLDS 384                 // YOFF + N + margin for N <= 240
#define BNDSZ 424                // absolute-diag-indexed boundary ring (max idx 417)
#define NW   4                   // waves per batch (one per SIMD)

// exp2/log2 via raw ISA (no fast-math dependence)
__device__ __forceinline__ float fexp2(float x){ float r; asm("v_exp_f32 %0, %1" : "=v"(r) : "v"(x)); return r; }
__device__ __forceinline__ float flog2(float x){ float r; asm("v_log_f32 %0, %1" : "=v"(r) : "v"(x)); return r; }

// Fused whole-wave shift + lane-0 boundary inject (validated R4-R12, absmax 0.0)
__device__ __forceinline__ float dpp_shr1_sel(float h, float src){
    int o = __builtin_bit_cast(int, h);
    int s = __builtin_bit_cast(int, src);
    int r = __builtin_amdgcn_update_dpp(o, s, 0x138 /*wave_shr:1*/, 0xF, 0xF, false);
    return __builtin_bit_cast(float, r);
}

// Soft-DTW cell, scaled domain R' = R*CSCL, qq precomputed off-chain.
// No boundary mask: invalid cells self-perpetuate at ~BIGP and contribute
// exactly 0.0f through exp2 in any valid cell (validated R4-R12, absmax 0.0).
__device__ __forceinline__ float dpcell(float up2, float up, float left, float qq) {
    float m  = fmaxf(fmaxf(up2, up), left);            // v_max3_f32
    float lo = fminf(fminf(up2, up), left);            // v_min3_f32
    float md = __builtin_amdgcn_fmed3f(up2, up, left); // v_med3_f32
    float e  = fexp2(lo - m) + fexp2(md - m) + 1.0f;
    float ls = flog2(e) + m;
    return ls + qq;
}

// R7 verbatim: barrier-free 4-wave lag pipeline (1 row/lane, 64 rows/stage,
// monotone LDS progress counters, producers never wait, trimmed spans,
// distance-1 software-pipelined group prefetch, launch_bounds(256,1)).
// Only addition: fused final 256->1 reduction (R9/R11's validated epilogue) —
// the last block to finish reduces ws[0..255], removing the second launch.
__global__ __launch_bounds__(256, 1)
void softdtw_wave(const float* __restrict__ x, const float* __restrict__ y,
                  float* __restrict__ ws, int* __restrict__ cnt,
                  float* __restrict__ out, int N) {
    const int b = blockIdx.x;
    const int t = threadIdx.x;          // 0..255
    const int l = t & 63;               // lane within wave
    const int w = t >> 6;               // wave 0..3

    __shared__ __align__(16) float Ys[YLDS];
    __shared__ float bnd[NW - 1][BNDSZ];
    __shared__ int prog[NW - 1];
    __shared__ float res_s;
    __shared__ int last_s;

    for (int j = t; j < YLDS; j += 256) Ys[j] = 0.f;
    float* bf = &bnd[0][0];
    for (int j = t; j < (NW - 1) * BNDSZ; j += 256) bf[j] = BIGP;
    if (t < NW - 1) prog[t] = 0;
    __syncthreads();
    for (int j = t; j < N; j += 256) Ys[YOFF + j] = y[j * STEP * NCH + b];
    __syncthreads();                    // startup-only block barriers

    const int i = 64 * w + l + 1;       // my row
    const float xv = (i <= N) ? x[(i - 1) * STEP * NCH + b] : 0.f;

    // scaled DP state entering diag s:
    //   sp = R'(i, s-1-i)   bp = R'(i-1, s-i)   bq = R'(i-1, s-1-i)
    float sp = BIGP, bp = BIGP;
    float bq = (t == 0) ? 0.0f : BIGP;  // R'[0][0] seed enters at s=2

    const int smax = 2 * N;
    const int sb0  = 64 * w + 2;        // first diagonal of this wave
    const int myrows = (64 * (w + 1) < N) ? 64 * (w + 1) : N;
    const int NG     = (myrows + N - sb0 + 1 + 7) >> 3;   // trimmed groups
    const bool prod = (w < NW - 1);
    const bool cons = (w > 0);
    const int prows = (64 * w < N) ? 64 * w : N;
    const int pNG   = (prows + N - (sb0 - 64) + 1 + 7) >> 3;
    const int progFinal = (sb0 - 64) + 8 * pNG - 1;       // producer's last diag

    const float* yrow = Ys + (YOFF - l);   // group m step J: yrow[8m + J]
    const float* bb = cons ? bnd[w - 1] : bnd[0];

    #define POLL(NEED) do {                                               \
        const int need_ = min((NEED), progFinal);                         \
        while (__hip_atomic_load(&prog[w - 1], __ATOMIC_ACQUIRE,          \
                                 __HIP_MEMORY_SCOPE_WORKGROUP) < need_)   \
            __builtin_amdgcn_s_sleep(1);                                  \
    } while (0)

    // ---- prologue: prefetch group 0 ----
    float q0,q1,q2,q3,q4,q5,q6,q7;      // qq = (xv - y)^2 * CSCL per step
    float h0,h1,h2,h3,h4,h5,h6,h7;      // boundary (row 64w) per step
    {
        float a0=yrow[0],a1=yrow[1],a2=yrow[2],a3=yrow[3];
        float a4=yrow[4],a5=yrow[5],a6=yrow[6],a7=yrow[7];
        if (cons) {
            POLL(sb0 + 7);
            if (l == 0) bp = bb[sb0 - 1];          // seed R'(64w, 1)
            h0=bb[sb0+0]; h1=bb[sb0+1]; h2=bb[sb0+2]; h3=bb[sb0+3];
            h4=bb[sb0+4]; h5=bb[sb0+5]; h6=bb[sb0+6]; h7=bb[sb0+7];
        } else {
            h0=h1=h2=h3=h4=h5=h6=h7 = BIGP;        // row-0 wall (constant)
        }
        float d;
        d=xv-a0; q0=d*CSCL*d;  d=xv-a1; q1=d*CSCL*d;
        d=xv-a2; q2=d*CSCL*d;  d=xv-a3; q3=d*CSCL*d;
        d=xv-a4; q4=d*CSCL*d;  d=xv-a5; q5=d*CSCL*d;
        d=xv-a6; q6=d*CSCL*d;  d=xv-a7; q7=d*CSCL*d;
    }

    #define STEPJ(QQ, HJ, CJ, J) do {                              \
        CJ = dpcell(bq, bp, sp, (QQ));                             \
        float n_ = dpp_shr1_sel((HJ), CJ);                         \
        bq = bp; bp = n_; sp = CJ;                                 \
        if (sb + (J) == smax && i == N) res_s = CJ * GLN2;         \
    } while (0)

    for (int m = 0; m < NG; ++m) {
        const int sb = sb0 + 8 * m;
        float c0,c1,c2,c3,c4,c5,c6,c7;
        STEPJ(q0, h0, c0, 0); STEPJ(q1, h1, c1, 1);
        STEPJ(q2, h2, c2, 2); STEPJ(q3, h3, c3, 3);
        STEPJ(q4, h4, c4, 4); STEPJ(q5, h5, c5, 5);
        STEPJ(q6, h6, c6, 6); STEPJ(q7, h7, c7, 7);

        // batched boundary publish from lane 63, one exec-mask toggle, release
        if (prod && l == 63) {
            float* bw = &bnd[w][sb];
            bw[0]=c0; bw[1]=c1; bw[2]=c2; bw[3]=c3;
            bw[4]=c4; bw[5]=c5; bw[6]=c6; bw[7]=c7;
            __hip_atomic_store(&prog[w], sb + 7, __ATOMIC_RELEASE,
                               __HIP_MEMORY_SCOPE_WORKGROUP);
        }

        // ---- prefetch group m+1 (y first — no sync dependency; then h) ----
        if (m + 1 < NG) {
            const float* yn = yrow + 8 * (m + 1);
            float a0=yn[0],a1=yn[1],a2=yn[2],a3=yn[3];
            float a4=yn[4],a5=yn[5],a6=yn[6],a7=yn[7];
            if (cons) {
                POLL(sb + 15);
                h0=bb[sb+8];  h1=bb[sb+9];  h2=bb[sb+10]; h3=bb[sb+11];
                h4=bb[sb+12]; h5=bb[sb+13]; h6=bb[sb+14]; h7=bb[sb+15];
            }
            float d;
            d=xv-a0; q0=d*CSCL*d;  d=xv-a1; q1=d*CSCL*d;
            d=xv-a2; q2=d*CSCL*d;  d=xv-a3; q3=d*CSCL*d;
            d=xv-a4; q4=d*CSCL*d;  d=xv-a5; q5=d*CSCL*d;
            d=xv-a6; q6=d*CSCL*d;  d=xv-a7; q7=d*CSCL*d;
        }
    }
    #undef STEPJ
    #undef POLL

    // ---- fused 256 -> 1 reduction: last finished block reduces ws ----
    // (validated in R9/R11: ws release + cnt ACQ_REL orders all blocks' stores
    //  before the last block's reads; reduction tree identical to reduce256)
    __syncthreads();                    // res_s written (by the i==N lane)
    if (t == 0) {
        __hip_atomic_store(&ws[b], res_s, __ATOMIC_RELEASE,
                           __HIP_MEMORY_SCOPE_AGENT);
        int prev = __hip_atomic_fetch_add(cnt, 1, __ATOMIC_ACQ_REL,
                                          __HIP_MEMORY_SCOPE_AGENT);
        last_s = (prev == NCH - 1);
    }
    __syncthreads();
    if (last_s) {                       // exactly one block runs this
        float v = __hip_atomic_load(&ws[t], __ATOMIC_RELAXED,
                                    __HIP_MEMORY_SCOPE_AGENT);
        #pragma unroll
        for (int off = 32; off > 0; off >>= 1)
            v += __shfl_down(v, off, 64);
        __shared__ float partial[4];
        if ((t & 63) == 0) partial[t >> 6] = v;
        __syncthreads();
        if (t == 0) out[0] = (partial[0] + partial[1]) + (partial[2] + partial[3]);
    }
}

extern "C" void kernel_launch(void* const* d_in, const int* in_sizes, int n_in,
                              void* d_out, int out_size, void* d_ws, size_t ws_size,
                              hipStream_t stream) {
    const float* x = (const float*)d_in[0];
    const float* y = (const float*)d_in[1];
    float* out = (float*)d_out;
    float* ws  = (float*)d_ws;
    int*   cnt = (int*)(ws + NCH);

    const int T = in_sizes[0] / NCH;            // 2048 frames
    const int L = (T + STEP - 1) / STEP;        // 205 subsampled frames

    hipMemsetAsync(cnt, 0, sizeof(int), stream);
    softdtw_wave<<<dim3(NCH), dim3(256), 0, stream>>>(x, y, ws, cnt, out, L);
}

// Round 14
// 38.119 us; speedup vs baseline: 1.2708x; 1.2708x over previous
//
#include <hip/hip_runtime.h>

#define STEP 10
#define NCH  256                 // 128*2 flattened channels = DP "batches"
#define CSCL (-144.2695041f)     // -(1/GAMMA)*log2(e): scale into log2 domain
#define GLN2 (-0.00693147181f)   // -GAMMA*ln(2) == 1/CSCL (to 7e-10 rel)
#define BIGP (-1.442695041e12f)  // 1e10 * CSCL : boundary "BIG" in scaled domain
#define YOFF 64                  // pad: y idx = s-64w-l-2 >= -63
#define YLDS 384                 // YOFF + N + 80 for N <= 240
#define BNDSZ 472                // absolute-diag-indexed boundary ring (no reuse)
#define NW   4                   // waves per batch

// exp2/log2 via raw ISA (no fast-math dependence)
__device__ __forceinline__ float fexp2(float x){ float r; asm("v_exp_f32 %0, %1" : "=v"(r) : "v"(x)); return r; }
__device__ __forceinline__ float flog2(float x){ float r; asm("v_log_f32 %0, %1" : "=v"(r) : "v"(x)); return r; }

// Whole-wave shift toward higher lanes (lane i <- lane i-1), VALU-speed DPP.
// Lane 0 gets 0 (bound_ctrl); caller overrides via select. Validated R4/R5.
__device__ __forceinline__ float dpp_shr1(float src){
    int s = __builtin_bit_cast(int, src);
    int r = __builtin_amdgcn_update_dpp(0, s, 0x138 /*wave_shr:1*/, 0xF, 0xF, true);
    return __builtin_bit_cast(float, r);
}

// Soft-DTW cell, scaled domain R' = R*CSCL, with qq = (x-y)^2*CSCL precomputed
// off the critical path. m+qq computes in parallel with log2(e) — chain is
// max3 -> sub -> exp2 -> add -> add -> log2 -> add. No boundary mask: invalid
// cells self-perpetuate at ~BIGP and contribute exactly 0.0f through exp2 in
// any valid cell (validated R4-R13, absmax 0.0).
__device__ __forceinline__ float dpcell(float up2, float up, float left, float qq) {
    float m  = fmaxf(fmaxf(up2, up), left);            // v_max3_f32
    float lo = fminf(fminf(up2, up), left);            // v_min3_f32
    float md = __builtin_amdgcn_fmed3f(up2, up, left); // v_med3_f32
    float e  = fexp2(lo - m) + fexp2(md - m) + 1.0f;
    float mq = m + qq;                                 // off-chain
    return flog2(e) + mq;
}

// R5's barrier-free 4-wave lag pipeline (1 row/lane, monotone LDS progress
// counters, producers never wait). R7 additions (the best-measured config):
//  - __launch_bounds__(256, 1): 1 block/CU anyway; lets the compiler keep all
//    prefetched values in registers instead of sinking ds_reads onto the chain.
//  - software-pipelined groups: y and boundary h for group m+1 are loaded at
//    the bottom of group m (poll first), so no LDS result is consumed in the
//    group that issued it.
//  - qq precomputed during the prefetch window.
//  - per-wave trimmed group counts (last needed diag = min(64(w+1),N)+N);
//    reads past a producer's trimmed span hit BIGP-initialized slots = correct.
__global__ __launch_bounds__(256, 1)
void softdtw_wave(const float* __restrict__ x, const float* __restrict__ y,
                  float* __restrict__ ws, int N) {
    const int b = blockIdx.x;
    const int t = threadIdx.x;          // 0..255
    const int l = t & 63;               // lane within wave
    const int w = t >> 6;               // wave 0..3

    __shared__ __align__(16) float Ys[YLDS];
    __shared__ float bnd[NW - 1][BNDSZ];
    __shared__ int prog[NW - 1];

    for (int j = t; j < YLDS; j += 256) Ys[j] = 0.f;
    float* bf = &bnd[0][0];
    for (int j = t; j < (NW - 1) * BNDSZ; j += 256) bf[j] = BIGP;
    if (t < NW - 1) prog[t] = 0;
    __syncthreads();
    for (int j = t; j < N; j += 256) Ys[YOFF + j] = y[j * STEP * NCH + b];
    __syncthreads();                    // the only block-wide barriers (startup)

    const int i = 64 * w + l + 1;       // my row
    const float xv = (i <= N) ? x[(i - 1) * STEP * NCH + b] : 0.f;

    // scaled DP state entering diag s:
    //   sp = R'(i, s-1-i)   bp = R'(i-1, s-i)   bq = R'(i-1, s-1-i)
    float sp = BIGP, bp = BIGP;
    float bq = (t == 0) ? 0.0f : BIGP;  // R'[0][0] seed enters at s=2

    const int smax = 2 * N;
    const int sb0  = 64 * w + 2;        // first diagonal of this wave
    // trimmed group count: last diag this wave needs = min(64(w+1), N) + N
    const int myrows = (64 * (w + 1) < N) ? 64 * (w + 1) : N;
    const int NG     = (myrows + N - sb0 + 1 + 7) >> 3;
    const bool prod = (w < NW - 1);
    const bool cons = (w > 0);
    // producer (w-1)'s trimmed final publish
    const int prows = (64 * w < N) ? 64 * w : N;
    const int pNG   = (prows + N - (sb0 - 64) + 1 + 7) >> 3;
    const int progFinal = (sb0 - 64) + 8 * pNG - 1;

    // per-lane y pointer: group m, step J reads yb[8m + J] = Ys[YOFF + sb+J-i-1]
    const float* yb = Ys + (YOFF - l);
    const float* bb = cons ? bnd[w - 1] : bnd[0];   // bb unused when !cons

    #define POLL(NEED) do {                                               \
        const int need_ = min((NEED), progFinal);                         \
        while (__hip_atomic_load(&prog[w - 1], __ATOMIC_ACQUIRE,          \
                                 __HIP_MEMORY_SCOPE_WORKGROUP) < need_)   \
            __builtin_amdgcn_s_sleep(1);                                  \
    } while (0)

    // ---- prologue: prefetch group 0 ----
    float q0,q1,q2,q3,q4,q5,q6,q7;      // qq = (xv - y)^2 * CSCL per step
    float h0,h1,h2,h3,h4,h5,h6,h7;      // boundary (row 64w) per step
    {
        float a0=yb[0],a1=yb[1],a2=yb[2],a3=yb[3];
        float a4=yb[4],a5=yb[5],a6=yb[6],a7=yb[7];
        if (cons) {
            POLL(sb0 + 7);
            if (l == 0) bp = bb[sb0 - 1];          // seed R'(64w, 1)
            h0=bb[sb0+0]; h1=bb[sb0+1]; h2=bb[sb0+2]; h3=bb[sb0+3];
            h4=bb[sb0+4]; h5=bb[sb0+5]; h6=bb[sb0+6]; h7=bb[sb0+7];
        } else {
            h0=h1=h2=h3=h4=h5=h6=h7 = BIGP;        // row-0 wall (constant)
        }
        float d;
        d=xv-a0; q0=d*CSCL*d;  d=xv-a1; q1=d*CSCL*d;
        d=xv-a2; q2=d*CSCL*d;  d=xv-a3; q3=d*CSCL*d;
        d=xv-a4; q4=d*CSCL*d;  d=xv-a5; q5=d*CSCL*d;
        d=xv-a6; q6=d*CSCL*d;  d=xv-a7; q7=d*CSCL*d;
    }

    #define STEPJ(QQ, HJ, CJ, J) do {                              \
        CJ = dpcell(bq, bp, sp, (QQ));                             \
        float sh = dpp_shr1(CJ);                                   \
        bq = bp;                                                   \
        bp = (l == 0) ? (HJ) : sh;                                 \
        sp = CJ;                                                   \
        if (sb + (J) == smax && i == N) ws[b] = CJ * GLN2;         \
    } while (0)

    for (int m = 0; m < NG; ++m) {
        const int sb = sb0 + 8 * m;
        float c0,c1,c2,c3,c4,c5,c6,c7;
        STEPJ(q0, h0, c0, 0); STEPJ(q1, h1, c1, 1);
        STEPJ(q2, h2, c2, 2); STEPJ(q3, h3, c3, 3);
        STEPJ(q4, h4, c4, 4); STEPJ(q5, h5, c5, 5);
        STEPJ(q6, h6, c6, 6); STEPJ(q7, h7, c7, 7);

        // batched boundary publish: one exec-mask toggle, 8 writes, release
        if (prod && l == 63) {
            float* bw = &bnd[w][sb];
            bw[0]=c0; bw[1]=c1; bw[2]=c2; bw[3]=c3;
            bw[4]=c4; bw[5]=c5; bw[6]=c6; bw[7]=c7;
            __hip_atomic_store(&prog[w], sb + 7, __ATOMIC_RELEASE,
                               __HIP_MEMORY_SCOPE_WORKGROUP);
        }

        // ---- prefetch group m+1 (y first — no sync dependency; then h) ----
        if (m + 1 < NG) {
            const float* yn = yb + 8 * (m + 1);
            float a0=yn[0],a1=yn[1],a2=yn[2],a3=yn[3];
            float a4=yn[4],a5=yn[5],a6=yn[6],a7=yn[7];
            if (cons) {
                POLL(sb + 15);
                h0=bb[sb+8];  h1=bb[sb+9];  h2=bb[sb+10]; h3=bb[sb+11];
                h4=bb[sb+12]; h5=bb[sb+13]; h6=bb[sb+14]; h7=bb[sb+15];
            }
            float d;
            d=xv-a0; q0=d*CSCL*d;  d=xv-a1; q1=d*CSCL*d;
            d=xv-a2; q2=d*CSCL*d;  d=xv-a3; q3=d*CSCL*d;
            d=xv-a4; q4=d*CSCL*d;  d=xv-a5; q5=d*CSCL*d;
            d=xv-a6; q6=d*CSCL*d;  d=xv-a7; q7=d*CSCL*d;
        }
    }
    #undef STEPJ
    #undef POLL
}

// Deterministic 256 -> 1 reduction (shuffle within wave64, LDS across 4 waves)
__global__ __launch_bounds__(256)
void reduce256(const float* __restrict__ ws, float* __restrict__ out) {
    const int tid = threadIdx.x;
    float v = ws[tid];
    #pragma unroll
    for (int off = 32; off > 0; off >>= 1)
        v += __shfl_down(v, off, 64);
    __shared__ float partial[4];
    if ((tid & 63) == 0) partial[tid >> 6] = v;
    __syncthreads();
    if (tid == 0) out[0] = (partial[0] + partial[1]) + (partial[2] + partial[3]);
}

extern "C" void kernel_launch(void* const* d_in, const int* in_sizes, int n_in,
                              void* d_out, int out_size, void* d_ws, size_t ws_size,
                              hipStream_t stream) {
    const float* x = (const float*)d_in[0];
    const float* y = (const float*)d_in[1];
    float* out = (float*)d_out;
    float* ws  = (float*)d_ws;

    const int T = in_sizes[0] / NCH;            // 2048 frames
    const int L = (T + STEP - 1) / STEP;        // 205 subsampled frames

    softdtw_wave<<<dim3(NCH), dim3(64 * NW), 0, stream>>>(x, y, ws, L);
    reduce256<<<dim3(1), dim3(256), 0, stream>>>(ws, out);
}